// Round 8
// baseline (112.254 us; speedup 1.0000x reference)
//
#include <hip/hip_runtime.h>
#include <math.h>

#define N 8192
// k_flags: 8 i-chunks (1024 i) x 32 j-slices (256 j) = 256 blocks = 1/CU
#define F_TPB 256
#define F_IT  4
#define F_IB  8
#define F_JS  32
#define F_SL  256
// k_rank: 256 blocks x 256 thr, 32 i's per block, 8 j-segments
#define R_TPB 256

// Reference f32 pipeline (verified absmax 0.0 in R2..R7):
//   i = round((log(512)-log(w))/log(1.2)); di = 128/1.2^i; qx = round(x/di-0.5)
// Bounds: i,j in [0,23] (5 bits), qx,qy in [0,1035] (11 bits).
// pack = (j<<27)|(i<<22)|(qy<<11)|qx is equality- AND order-isomorphic to the
// reference decimal int64 code (decimal fields never carry: 1035<1e4, 23<1e4).
// s_pow[k] = (float)pow((double)1.2f,(double)k) is bit-identical to the
// verified per-thread pow((double)1.2f,(double)i_f) calls.
__device__ __forceinline__ unsigned pack_code_tab(float x, float y, float w, float h,
                                                  const float* __restrict__ s_pow) {
    const float LOG_ALPHA = (float)log((double)1.2f);
    const float LOGW0     = (float)log(512.0);
    float i_f = rintf((LOGW0 - (float)log((double)w)) / LOG_ALPHA);
    float j_f = rintf((LOGW0 - (float)log((double)h)) / LOG_ALPHA);
    int ii = (int)i_f, jj = (int)j_f;
    float qx = rintf(x / (128.0f / s_pow[ii]) - 0.5f);
    float qy = rintf(y / (128.0f / s_pow[jj]) - 0.5f);
    return ((unsigned)jj << 27) | ((unsigned)ii << 22)
         | ((unsigned)(int)qy << 11) | (unsigned)(int)qx;
}

// k_flags: block (ib,js) stages 256 j-keys in LDS; each thread holds 4 i-keys
// in registers (one ds_read amortized over 8 compares via ulonglong2 + IT=4).
// j beats i iff same code && (conf_j>conf_i || (conf_j==conf_i && j<i)):
//   w=(code<<32)|conf_bits: beat = (wj>wi && wj<bd) || (wj==wi && j<i),
//   bd=(code_i+1)<<32  (R5-verified form).
// Writes byte partial flagrow[i*32+js]; js==0 publishes code32 and zeroes out.
__global__ void __launch_bounds__(F_TPB)
k_flags(const float4* __restrict__ rects, const float* __restrict__ conf,
        unsigned* __restrict__ code32, unsigned char* __restrict__ flagrow,
        int* __restrict__ out) {
    __shared__ unsigned long long s_w[F_SL];
    __shared__ float s_pow[24];
    const int t = threadIdx.x, ib = blockIdx.x, js = blockIdx.y;
    const int jb = js * F_SL;

    if (t < 24) s_pow[t] = (float)pow((double)1.2f, (double)t);
    __syncthreads();

    // stage this slice's 256 j-keys (1 per thread, coalesced float4 load)
    {
        float4 rj = rects[jb + t];
        unsigned cj = pack_code_tab(rj.x, rj.y, rj.z, rj.w, s_pow);
        s_w[t] = ((unsigned long long)cj << 32)
               | (unsigned long long)__float_as_uint(conf[jb + t]);
    }
    // own 4 i-keys (recomputed per block; identical math everywhere)
    unsigned long long wi[F_IT], bd[F_IT];
    int ii[F_IT];
    #pragma unroll
    for (int m = 0; m < F_IT; ++m) {
        int i = ib * (F_TPB * F_IT) + m * F_TPB + t;
        ii[m] = i;
        float4 ri = rects[i];
        unsigned ci = pack_code_tab(ri.x, ri.y, ri.z, ri.w, s_pow);
        wi[m] = ((unsigned long long)ci << 32)
              | (unsigned long long)__float_as_uint(conf[i]);
        bd[m] = (wi[m] | 0xFFFFFFFFULL) + 1ULL;
        if (js == 0) { code32[i] = ci; out[i] = 0; }  // padded slots must be 0
    }
    __syncthreads();

    int l[F_IT] = {0, 0, 0, 0};
    const ulonglong2* s2 = (const ulonglong2*)s_w;
    #pragma unroll 4
    for (int k = 0; k < F_SL / 2; ++k) {
        ulonglong2 wj = s2[k];                    // b128 wave-uniform broadcast
        int jg0 = jb + 2 * k, jg1 = jg0 + 1;
        #pragma unroll
        for (int m = 0; m < F_IT; ++m) {
            l[m] |= (int)(((wj.x > wi[m]) & (wj.x < bd[m])) |
                          ((wj.x == wi[m]) & (jg0 < ii[m])));
            l[m] |= (int)(((wj.y > wi[m]) & (wj.y < bd[m])) |
                          ((wj.y == wi[m]) & (jg1 < ii[m])));
        }
    }
    #pragma unroll
    for (int m = 0; m < F_IT; ++m)
        flagrow[ii[m] * F_JS + js] = (unsigned char)l[m];
}

// k_rank: stage winner-masked codes for ALL j (OR-reducing the 32 flag bytes
// inline, coalesced uint4), then 8 segs x 32 i count code_j < code_i via
// ds_read_b128 (2-way multicast per wave: free). rank = #distinct codes below
// mine (exactly one winner per distinct code). Winners scatter out[rank]=i.
__global__ void __launch_bounds__(R_TPB)
k_rank(const unsigned* __restrict__ code32, const uint4* __restrict__ flagv,
       const float* __restrict__ conf, int* __restrict__ out) {
    __shared__ unsigned s_v[N];                   // 32 KiB
    __shared__ int s_r[R_TPB];
    const int t = threadIdx.x, b = blockIdx.x;

    #pragma unroll 4
    for (int c = 0; c < N / R_TPB; ++c) {         // 32 j's per thread
        int j = t + c * R_TPB;
        uint4 f0 = flagv[2 * j], f1 = flagv[2 * j + 1];   // 32 lose bytes
        unsigned lose = f0.x | f0.y | f0.z | f0.w | f1.x | f1.y | f1.z | f1.w;
        // losers -> 0xFFFFFFFF (> any real code < 0xC0000000): never counted
        s_v[j] = lose ? 0xFFFFFFFFu : code32[j];
    }
    __syncthreads();

    const int il = t & 31, seg = t >> 5;
    const int i = b * 32 + il;
    unsigned ci = s_v[i];                         // losers get garbage r: unused
    const uint4* sv4 = (const uint4*)&s_v[seg * 1024];
    int r = 0;
    #pragma unroll 8
    for (int k = 0; k < 256; ++k) {
        uint4 v = sv4[k];
        r += (int)(v.x < ci) + (int)(v.y < ci) + (int)(v.z < ci) + (int)(v.w < ci);
    }
    s_r[seg * 32 + il] = r;
    __syncthreads();

    if (t < 32) {
        int gi = b * 32 + t;
        int rr = 0;
        #pragma unroll
        for (int s = 0; s < 8; ++s) rr += s_r[s * 32 + t];
        if (s_v[gi] != 0xFFFFFFFFu) {             // winner
            // conf==0 edge: all-zero score column -> reference argmax -> 0
            out[rr] = (conf[gi] == 0.0f) ? 0 : gi;
        }
    }
}

extern "C" void kernel_launch(void* const* d_in, const int* in_sizes, int n_in,
                              void* d_out, int out_size, void* d_ws, size_t ws_size,
                              hipStream_t stream) {
    const float4* rects = (const float4*)d_in[0];   // (8192, 4) f32
    const float*  conf  = (const float*)d_in[1];    // (8192,)  f32
    int* out = (int*)d_out;                         // int32 indices

    char* ws = (char*)d_ws;
    unsigned*      code32  = (unsigned*)ws;                   // 32 KiB
    unsigned char* flagrow = (unsigned char*)(ws + N * 4);    // 256 KiB (32 B/i)

    k_flags<<<dim3(F_IB, F_JS), F_TPB, 0, stream>>>(rects, conf, code32, flagrow, out);
    k_rank <<<dim3(N / 32),     R_TPB, 0, stream>>>(code32, (const uint4*)flagrow, conf, out);
}